// Round 6
// baseline (10304.479 us; speedup 1.0000x reference)
//
#include <hip/hip_runtime.h>
#include <math.h>

// MultilayerLSTM: B=16, S=512, D_IN=512, D_H=1024, D_OUT=2, VOCAB=32000
// Round 5: back to the PROVEN round-2 single-grid structure (64 blocks,
// wave=gate, MFMA 16x16x32, W persistent in VGPRs), but the per-step grid
// barrier is now FENCE-FREE: H is exchanged via volatile (sc0 sc1 -> bypass
// L1+L2, coherent at MALL) loads/stores, and the barrier is a plain
// device-scope atomicAdd + volatile poll. No per-step L2 writeback/invalidate.

#define BB   16
#define SLEN 512
#define DIN  512
#define DH   1024

typedef __attribute__((ext_vector_type(8))) short short8;
typedef __attribute__((ext_vector_type(4))) float f32x4;

__device__ inline unsigned short f2bfbits(float x) {
  union { float f; unsigned u; } v; v.f = x;
  unsigned r = v.u + 0x7FFF + ((v.u >> 16) & 1);  // RNE
  return (unsigned short)(r >> 16);
}

// ---------------- zero counters ----------------
__global__ void zero_cnt_kernel(unsigned* cnt) {
  if (threadIdx.x < 8) cnt[threadIdx.x] = 0;
}

// ---------------- embedding gather ----------------
__global__ __launch_bounds__(256) void embed_kernel(const int* __restrict__ tokens,
                                                    const float* __restrict__ emb,
                                                    float* __restrict__ x0) {
  int idx = blockIdx.x * 256 + threadIdx.x;  // over 8192*128 float4s
  int r = idx >> 7, d4 = idx & 127;
  int tok = tokens[r];
  const float4* src = (const float4*)emb + (((size_t)tok) << 7) + d4;
  ((float4*)x0)[(((size_t)r) << 7) + d4] = *src;
}

// ---------------- xproj GEMM: C[M][4096] = A[M][K] @ W_g[K][1024] + b_g ----------------
__global__ __launch_bounds__(256) void xproj_kernel(
    const float* __restrict__ A, int K,
    const float* __restrict__ Wi, const float* __restrict__ Wf,
    const float* __restrict__ Wg, const float* __restrict__ Wo,
    const float* __restrict__ bi, const float* __restrict__ bf,
    const float* __restrict__ bg, const float* __restrict__ bo,
    float* __restrict__ Cout)
{
  __shared__ float As[8][128];
  __shared__ float Bs[8][128];
  const int tid = threadIdx.x;
  const int bn = blockIdx.x;   // 0..31
  const int bm = blockIdx.y;   // 0..63
  const int m0 = bm * 128;
  const int n0 = bn * 128;
  const int g = n0 >> 10;
  const float* W    = (g == 0) ? Wi : (g == 1) ? Wf : (g == 2) ? Wg : Wo;
  const float* bias = (g == 0) ? bi : (g == 1) ? bf : (g == 2) ? bg : bo;
  const int col0 = n0 & 1023;
  const int tx = tid & 15, ty = tid >> 4;
  const int lr = tid >> 1, lh = tid & 1;          // A-tile loader
  const int lk = tid >> 5, ln = (tid & 31) << 2;  // B-tile loader

  float acc[8][8];
#pragma unroll
  for (int i = 0; i < 8; ++i)
#pragma unroll
    for (int j = 0; j < 8; ++j) acc[i][j] = 0.f;

  for (int k0 = 0; k0 < K; k0 += 8) {
    float4 av = *(const float4*)(A + (size_t)(m0 + lr) * K + k0 + lh * 4);
    float4 bv = *(const float4*)(W + (size_t)(k0 + lk) * 1024 + col0 + ln);
    As[lh * 4 + 0][lr] = av.x;
    As[lh * 4 + 1][lr] = av.y;
    As[lh * 4 + 2][lr] = av.z;
    As[lh * 4 + 3][lr] = av.w;
    *(float4*)&Bs[lk][ln] = bv;
    __syncthreads();
#pragma unroll
    for (int p = 0; p < 8; ++p) {
      float a[8], b[8];
      *(float4*)&a[0] = *(const float4*)&As[p][ty * 8];
      *(float4*)&a[4] = *(const float4*)&As[p][ty * 8 + 4];
      *(float4*)&b[0] = *(const float4*)&Bs[p][tx * 4];
      *(float4*)&b[4] = *(const float4*)&Bs[p][64 + tx * 4];
#pragma unroll
      for (int i = 0; i < 8; ++i)
#pragma unroll
        for (int j = 0; j < 8; ++j) acc[i][j] += a[i] * b[j];
    }
    __syncthreads();
  }
  float4 bA = *(const float4*)(bias + col0 + tx * 4);
  float4 bB = *(const float4*)(bias + col0 + 64 + tx * 4);
#pragma unroll
  for (int i = 0; i < 8; ++i) {
    int m = m0 + ty * 8 + i;
    float* crow = Cout + (((size_t)m) << 12) + n0;
    float4 o1 = make_float4(acc[i][0] + bA.x, acc[i][1] + bA.y, acc[i][2] + bA.z, acc[i][3] + bA.w);
    float4 o2 = make_float4(acc[i][4] + bB.x, acc[i][5] + bB.y, acc[i][6] + bB.z, acc[i][7] + bB.w);
    *(float4*)(crow + tx * 4) = o1;
    *(float4*)(crow + 64 + tx * 4) = o2;
  }
}

// ---------------- MFMA persistent LSTM recurrence (fence-free barrier) ------
// 64 blocks x 256 threads. Block owns hidden cols c0 = blockIdx.x*16 .. +15.
// Wave g (tid>>6) = gate g. Per step per wave: 32x mfma_f32_16x16x32_bf16.
// H exchanged via VOLATILE (sc0 sc1, MALL-coherent) loads/stores; barrier is
// plain device-scope atomicAdd + volatile poll. No fences anywhere.
__global__ __launch_bounds__(256, 1) void lstm_rec_mfma(
    const float* __restrict__ xp,
    const float* __restrict__ Wi, const float* __restrict__ Wf,
    const float* __restrict__ Wg, const float* __restrict__ Wo,
    int D,
    short* __restrict__ hb16,        // bf16 bits [t][b][1024]
    float* __restrict__ hf32,        // f32 [b][t][1024]
    unsigned* __restrict__ cnt)
{
  __shared__ float Pre[4][16][16];
  const int tid  = threadIdx.x;
  const int wv   = tid >> 6;         // gate
  const int lane = tid & 63;
  const int q    = lane >> 4;        // quad
  const int n    = lane & 15;        // output col within tile
  const int c0   = blockIdx.x << 4;
  const float* Wsel = (wv == 0) ? Wi : (wv == 1) ? Wf : (wv == 2) ? Wg : Wo;

  // persistent B-frags: wfrag[kk] holds W[D + kk*32 + q*8 + j][c0+n], j=0..7
  short8 wfrag[32];
#pragma unroll
  for (int kk = 0; kk < 32; ++kk) {
#pragma unroll
    for (int j = 0; j < 8; ++j) {
      float w = Wsel[(size_t)(D + kk * 32 + q * 8 + j) * 1024 + c0 + n];
      wfrag[kk][j] = (short)f2bfbits(w);
    }
  }

  const int cb = tid >> 4, cc = tid & 15;  // cell-update mapping
  float Creg = 0.f;

  // prologue xp for t=0
  float xv[4];
#pragma unroll
  for (int r = 0; r < 4; ++r)
    xv[r] = xp[(((size_t)((q * 4 + r) * SLEN)) << 12) + (wv << 10) + c0 + n];

  for (int t = 0; t < SLEN; ++t) {
    f32x4 acc;
#pragma unroll
    for (int r = 0; r < 4; ++r) acc[r] = xv[r];

    if (t > 0) {
      // volatile A-frag loads: bypass L1/L2, read coherent MALL copy
      const volatile short8* hb =
          (const volatile short8*)(hb16 + (((size_t)(t - 1)) << 14) + n * 1024 + q * 8);
#pragma unroll
      for (int kk = 0; kk < 32; ++kk) {
        short8 af = hb[kk * 4];  // stride 32 shorts = 4 short8
        acc = __builtin_amdgcn_mfma_f32_16x16x32_bf16(af, wfrag[kk], acc, 0, 0, 0);
      }
    }

    // prefetch xp for t+1 (plain cached load; completes during barrier)
    if (t + 1 < SLEN) {
#pragma unroll
      for (int r = 0; r < 4; ++r)
        xv[r] = xp[(((size_t)((q * 4 + r) * SLEN + t + 1)) << 12) + (wv << 10) + c0 + n];
    }

    // exchange preacts via LDS
#pragma unroll
    for (int r = 0; r < 4; ++r) Pre[wv][q * 4 + r][n] = acc[r];
    __syncthreads();

    // cell update: thread (cb, cc)
    float pI = Pre[0][cb][cc];
    float pF = Pre[1][cb][cc];
    float pG = Pre[2][cb][cc];
    float pO = Pre[3][cb][cc];
    float gI = 1.f / (1.f + __expf(-pI));
    float gF = 1.f / (1.f + __expf(-pF));
    float gG = tanhf(pG);
    float gO = 1.f / (1.f + __expf(-pO));
    Creg = gF * Creg + gI * gG;
    float h = gO * tanhf(Creg);

    // f32 store [b][t][k] for xproj(l1)/head (plain; kernel boundary flushes)
    hf32[(((size_t)(cb * SLEN + t)) << 10) + c0 + cc] = h;
    // bf16 volatile store [t][b][k]: pack pairs via shfl (tid^1 same wave)
    unsigned mybits = (unsigned)f2bfbits(h);
    unsigned nbbits = (unsigned)__shfl_xor((int)mybits, 1, 64);
    if ((cc & 1) == 0) {
      unsigned pk = mybits | (nbbits << 16);
      *(volatile unsigned*)(hb16 + (((size_t)(t * 16 + cb)) << 10) + c0 + cc) = pk;
    }
    __syncthreads();  // drains vmcnt(0): all waves' volatile stores acked at MALL

    // fence-free grid barrier: device-scope atomicAdd + volatile poll
    if (t + 1 < SLEN) {
      if (tid == 0) {
        atomicAdd(cnt, 1u);
        const unsigned target = 64u * (unsigned)(t + 1);
        int spins = 0;
        while (*(volatile unsigned*)cnt < target && spins < (1 << 16)) {
          __builtin_amdgcn_s_sleep(1);
          ++spins;
        }
      }
      __syncthreads();
    }
  }
}

// ---------------- FC head + log_softmax (D_OUT=2) ----------------
__global__ __launch_bounds__(256) void head_kernel(const float* __restrict__ h,
                                                   const float* __restrict__ Wfc,
                                                   const float* __restrict__ bfc,
                                                   float* __restrict__ out)
{
  const int lane = threadIdx.x & 63;
  const int row = blockIdx.x * 4 + (threadIdx.x >> 6);
  const float* hr = h + (((size_t)row) << 10);
  float s0 = 0.f, s1 = 0.f;
#pragma unroll
  for (int i = 0; i < 16; ++i) {
    int k = lane + i * 64;
    float hv = hr[k];
    float2 w = *(const float2*)(Wfc + 2 * k);
    s0 += hv * w.x;
    s1 += hv * w.y;
  }
#pragma unroll
  for (int off = 32; off > 0; off >>= 1) {
    s0 += __shfl_down(s0, off);
    s1 += __shfl_down(s1, off);
  }
  if (lane == 0) {
    s0 += bfc[0];
    s1 += bfc[1];
    float m = fmaxf(s0, s1);
    float lse = m + logf(expf(s0 - m) + expf(s1 - m));
    out[((size_t)row << 1) + 0] = s0 - lse;
    out[((size_t)row << 1) + 1] = s1 - lse;
  }
}

extern "C" void kernel_launch(void* const* d_in, const int* in_sizes, int n_in,
                              void* d_out, int out_size, void* d_ws, size_t ws_size,
                              hipStream_t stream)
{
  const int*   tokens = (const int*)d_in[0];
  const float* emb = (const float*)d_in[1];
  const float* W0i = (const float*)d_in[2];
  const float* b0i = (const float*)d_in[3];
  const float* W0f = (const float*)d_in[4];
  const float* b0f = (const float*)d_in[5];
  const float* W0g = (const float*)d_in[6];
  const float* b0g = (const float*)d_in[7];
  const float* W0o = (const float*)d_in[8];
  const float* b0o = (const float*)d_in[9];
  const float* W1i = (const float*)d_in[10];
  const float* b1i = (const float*)d_in[11];
  const float* W1f = (const float*)d_in[12];
  const float* b1f = (const float*)d_in[13];
  const float* W1g = (const float*)d_in[14];
  const float* b1g = (const float*)d_in[15];
  const float* W1o = (const float*)d_in[16];
  const float* b1o = (const float*)d_in[17];
  const float* Wfc = (const float*)d_in[18];
  const float* bfc = (const float*)d_in[19];
  float* out = (float*)d_out;

  float* ws = (float*)d_ws;
  float* x0 = ws;                               // 8192*512 f32; aliased as bf16 h [t][b][1024]
  float* h0 = x0 + (size_t)8192 * 512;          // 8192*1024 f32 [b][t][k] (both layers)
  float* xp = h0 + (size_t)8192 * 1024;         // 8192*4096 f32 (both layers)
  unsigned* cnt = (unsigned*)(xp + (size_t)8192 * 4096);  // 8 u32
  short* hb16 = (short*)x0;                     // 512*16*1024 bf16 = 16 MB (aliases x0)

  zero_cnt_kernel<<<1, 64, 0, stream>>>(cnt);
  embed_kernel<<<4096, 256, 0, stream>>>(tokens, emb, x0);
  xproj_kernel<<<dim3(32, 64), 256, 0, stream>>>(x0, 512,  W0i, W0f, W0g, W0o,
                                                 b0i, b0f, b0g, b0o, xp);
  // rec(l0): writes hb16 over x0 (x0 fully consumed by xproj above)
  lstm_rec_mfma<<<64, 256, 0, stream>>>(xp, W0i, W0f, W0g, W0o, 512, hb16, h0, cnt);
  xproj_kernel<<<dim3(32, 64), 256, 0, stream>>>(h0, 1024, W1i, W1f, W1g, W1o,
                                                 b1i, b1f, b1g, b1o, xp);
  lstm_rec_mfma<<<64, 256, 0, stream>>>(xp, W1i, W1f, W1g, W1o, 1024, hb16, h0, cnt + 1);
  head_kernel<<<2048, 256, 0, stream>>>(h0, Wfc, bfc, out);
}